// Round 1
// baseline (840.119 us; speedup 1.0000x reference)
//
#include <hip/hip_runtime.h>
#include <hip/hip_bf16.h>

#define IN_F   4096
#define OUT_F  4096
#define M_ROWS 8192
#define RANK   16
#define SCALING 2.0f

typedef __attribute__((ext_vector_type(8))) short bf16x8;
typedef __attribute__((ext_vector_type(4))) float f32x4;

__device__ __forceinline__ short f2b(float f) {
    union { float f; unsigned u; } c; c.f = f;
    unsigned r = (c.u + 0x7FFFu + ((c.u >> 16) & 1u)) >> 16;
    return (short)r;
}

__device__ __forceinline__ float4 ld4(const float* p) { return *(const float4*)p; }

__device__ __forceinline__ float4 s4(float4 v, float s) {
    v.x *= s; v.y *= s; v.z *= s; v.w *= s; return v;
}

__device__ __forceinline__ bf16x8 pack8(float4 a, float4 b) {
    bf16x8 r;
    r[0] = f2b(a.x); r[1] = f2b(a.y); r[2] = f2b(a.z); r[3] = f2b(a.w);
    r[4] = f2b(b.x); r[5] = f2b(b.y); r[6] = f2b(b.z); r[7] = f2b(b.w);
    return r;
}

// ---------------- Kernel 1: T = x @ lora_A^T   [M_ROWS, RANK] fp32 ----------------
// one thread per output element; 16 rr-threads share the same x row (L1 broadcast)
__global__ __launch_bounds__(256) void lora_t_kernel(const float* __restrict__ x,
                                                     const float* __restrict__ lora_A,
                                                     float* __restrict__ T) {
    const int t   = threadIdx.x;
    const int row = blockIdx.x * 16 + (t >> 4);
    const int rr  = t & 15;
    const float* xr = x + (size_t)row * IN_F;
    const float* ar = lora_A + (size_t)rr * IN_F;
    float acc = 0.f;
#pragma unroll 8
    for (int k = 0; k < IN_F; k += 4) {
        float4 xv = ld4(xr + k);
        float4 av = ld4(ar + k);
        acc += xv.x * av.x + xv.y * av.y + xv.z * av.z + xv.w * av.w;
    }
    T[row * RANK + rr] = acc;
}

// ---------------- Kernel 2: out = x @ W^T + bias + (scaling*T) @ lora_B^T ----------------
// 128x128 tile, BK=32, 4 waves (each 64x64), 16x16x32 bf16 MFMA, fp32->bf16 reg-staged.
__global__ __launch_bounds__(256) void lora_gemm_kernel(
        const float* __restrict__ x, const float* __restrict__ w,
        const float* __restrict__ bias, const float* __restrict__ lora_B,
        const float* __restrict__ T, float* __restrict__ out) {

    __shared__ __align__(16) short As[128][32];
    __shared__ __align__(16) short Bs[128][32];

    const int t    = threadIdx.x;
    const int brow = blockIdx.y * 128;
    const int bcol = blockIdx.x * 128;

    // staging assignment: thread -> (row, 16-element half of the 32-wide K slice)
    const int srow  = t >> 1;
    const int shalf = (t & 1) << 4;   // element offset 0 or 16

    const float* xa = x + (size_t)(brow + srow) * IN_F + shalf;
    const float* wb = w + (size_t)(bcol + srow) * IN_F + shalf;

    // wave/fragment assignment
    const int lane = t & 63;
    const int wv   = t >> 6;
    const int wr   = wv >> 1, wc = wv & 1;   // 2x2 wave grid, each 64x64
    const int l15  = lane & 15, lk = lane >> 4;

    f32x4 acc[4][4];
#pragma unroll
    for (int m = 0; m < 4; m++)
#pragma unroll
        for (int n = 0; n < 4; n++)
            acc[m][n] = (f32x4){0.f, 0.f, 0.f, 0.f};

    for (int k0 = 0; k0 < IN_F; k0 += 32) {
        // issue global loads early (fp32)
        float4 a0 = ld4(xa + k0);      float4 a1 = ld4(xa + k0 + 4);
        float4 a2 = ld4(xa + k0 + 8);  float4 a3 = ld4(xa + k0 + 12);
        float4 b0 = ld4(wb + k0);      float4 b1 = ld4(wb + k0 + 4);
        float4 b2 = ld4(wb + k0 + 8);  float4 b3 = ld4(wb + k0 + 12);

        __syncthreads();   // previous iteration's compute done
        *(bf16x8*)&As[srow][shalf]     = pack8(a0, a1);
        *(bf16x8*)&As[srow][shalf + 8] = pack8(a2, a3);
        *(bf16x8*)&Bs[srow][shalf]     = pack8(b0, b1);
        *(bf16x8*)&Bs[srow][shalf + 8] = pack8(b2, b3);
        __syncthreads();   // staging visible

        bf16x8 af[4], bf[4];
#pragma unroll
        for (int m = 0; m < 4; m++) af[m] = *(bf16x8*)&As[wr * 64 + m * 16 + l15][lk * 8];
#pragma unroll
        for (int n = 0; n < 4; n++) bf[n] = *(bf16x8*)&Bs[wc * 64 + n * 16 + l15][lk * 8];

#pragma unroll
        for (int m = 0; m < 4; m++)
#pragma unroll
            for (int n = 0; n < 4; n++)
                acc[m][n] = __builtin_amdgcn_mfma_f32_16x16x32_bf16(af[m], bf[n], acc[m][n], 0, 0, 0);
    }

    // ---- LoRA rank-update as one extra MFMA K-step ----
    // As <- scaling * T   (128 x 16, zero-padded to K=32)
    // Bs <- lora_B        (128 x 16, zero-padded to K=32)
    __syncthreads();
    if (shalf == 0) {
        const float* tp = T + (size_t)(brow + srow) * RANK;
        *(bf16x8*)&As[srow][0] = pack8(s4(ld4(tp), SCALING), s4(ld4(tp + 4), SCALING));
        *(bf16x8*)&As[srow][8] = pack8(s4(ld4(tp + 8), SCALING), s4(ld4(tp + 12), SCALING));
        const float* bp = lora_B + (size_t)(bcol + srow) * RANK;
        *(bf16x8*)&Bs[srow][0] = pack8(ld4(bp), ld4(bp + 4));
        *(bf16x8*)&Bs[srow][8] = pack8(ld4(bp + 8), ld4(bp + 12));
    } else {
        bf16x8 z;
#pragma unroll
        for (int i = 0; i < 8; i++) z[i] = 0;
        *(bf16x8*)&As[srow][16] = z; *(bf16x8*)&As[srow][24] = z;
        *(bf16x8*)&Bs[srow][16] = z; *(bf16x8*)&Bs[srow][24] = z;
    }
    __syncthreads();
    {
        bf16x8 af[4], bf[4];
#pragma unroll
        for (int m = 0; m < 4; m++) af[m] = *(bf16x8*)&As[wr * 64 + m * 16 + l15][lk * 8];
#pragma unroll
        for (int n = 0; n < 4; n++) bf[n] = *(bf16x8*)&Bs[wc * 64 + n * 16 + l15][lk * 8];
#pragma unroll
        for (int m = 0; m < 4; m++)
#pragma unroll
            for (int n = 0; n < 4; n++)
                acc[m][n] = __builtin_amdgcn_mfma_f32_16x16x32_bf16(af[m], bf[n], acc[m][n], 0, 0, 0);
    }

    // ---- epilogue: + bias, write C ----
    const int ocol0 = bcol + wc * 64 + l15;
#pragma unroll
    for (int n = 0; n < 4; n++) {
        const int col = ocol0 + n * 16;
        const float bv = bias[col];
#pragma unroll
        for (int m = 0; m < 4; m++) {
            const int row0 = brow + wr * 64 + m * 16 + lk * 4;
#pragma unroll
            for (int v = 0; v < 4; v++) {
                out[(size_t)(row0 + v) * OUT_F + col] = acc[m][n][v] + bv;
            }
        }
    }
}

extern "C" void kernel_launch(void* const* d_in, const int* in_sizes, int n_in,
                              void* d_out, int out_size, void* d_ws, size_t ws_size,
                              hipStream_t stream) {
    const float* x      = (const float*)d_in[0];
    const float* w      = (const float*)d_in[1];
    const float* bias   = (const float*)d_in[2];
    const float* lora_A = (const float*)d_in[3];
    const float* lora_B = (const float*)d_in[4];
    float* out = (float*)d_out;
    float* T   = (float*)d_ws;   // M_ROWS*RANK fp32 = 512 KiB scratch

    lora_t_kernel<<<M_ROWS / 16, 256, 0, stream>>>(x, lora_A, T);

    dim3 grid(OUT_F / 128, M_ROWS / 128);
    lora_gemm_kernel<<<grid, 256, 0, stream>>>(x, w, bias, lora_B, T, out);
}

// Round 2
// 470.085 us; speedup vs baseline: 1.7872x; 1.7872x over previous
//
#include <hip/hip_runtime.h>
#include <hip/hip_bf16.h>

#define IN_F   4096
#define OUT_F  4096
#define M_ROWS 8192
#define RANK   16
#define SCALING 2.0f

typedef __attribute__((ext_vector_type(8))) short bf16x8;
typedef __attribute__((ext_vector_type(4))) float f32x4;
typedef unsigned short ushort_t;

__device__ __forceinline__ short f2b(float f) {
    union { float f; unsigned u; } c; c.f = f;
    unsigned r = (c.u + 0x7FFFu + ((c.u >> 16) & 1u)) >> 16;
    return (short)r;
}

__device__ __forceinline__ float4 ld4(const float* p) { return *(const float4*)p; }

__device__ __forceinline__ float4 s4(float4 v, float s) {
    v.x *= s; v.y *= s; v.z *= s; v.w *= s; return v;
}

__device__ __forceinline__ bf16x8 pack8(float4 a, float4 b) {
    bf16x8 r;
    r[0] = f2b(a.x); r[1] = f2b(a.y); r[2] = f2b(a.z); r[3] = f2b(a.w);
    r[4] = f2b(b.x); r[5] = f2b(b.y); r[6] = f2b(b.z); r[7] = f2b(b.w);
    return r;
}

// async global->LDS, 16B per lane, dest = wave-uniform base + lane*16
__device__ __forceinline__ void gload16(const void* g, void* l) {
    __builtin_amdgcn_global_load_lds(
        (const __attribute__((address_space(1))) unsigned int*)g,
        (__attribute__((address_space(3))) unsigned int*)l, 16, 0, 0);
}

// ---------------- fp32 -> bf16 convert (grid-stride, 8 elems/thread/iter) ----------------
__global__ __launch_bounds__(256) void cvt_bf16_kernel(const float* __restrict__ in,
                                                       ushort_t* __restrict__ out, int n8) {
    int i = blockIdx.x * blockDim.x + threadIdx.x;
    const int stride = gridDim.x * blockDim.x;
    for (; i < n8; i += stride) {
        const float* p = in + (size_t)i * 8;
        *(bf16x8*)(out + (size_t)i * 8) = pack8(ld4(p), ld4(p + 4));
    }
}

// ---------------- T = x @ lora_A^T via MFMA, 1 wave -> 16 rows x 16 ranks ----------------
__global__ __launch_bounds__(256) void lora_t_mfma(const ushort_t* __restrict__ xb,
                                                   const ushort_t* __restrict__ ab,
                                                   float* __restrict__ T) {
    const int t = threadIdx.x, lane = t & 63, wv = t >> 6;
    const int r0 = blockIdx.x * 64 + wv * 16;
    const int l15 = lane & 15, lk = lane >> 4;
    const ushort_t* xr = xb + (size_t)(r0 + l15) * IN_F + lk * 8;
    const ushort_t* ar = ab + (size_t)l15 * IN_F + lk * 8;
    f32x4 acc = (f32x4){0.f, 0.f, 0.f, 0.f};
    for (int k0 = 0; k0 < IN_F; k0 += 32) {
        bf16x8 af = *(const bf16x8*)(xr + k0);
        bf16x8 bf = *(const bf16x8*)(ar + k0);
        acc = __builtin_amdgcn_mfma_f32_16x16x32_bf16(af, bf, acc, 0, 0, 0);
    }
#pragma unroll
    for (int v = 0; v < 4; v++)
        T[(size_t)(r0 + lk * 4 + v) * RANK + l15] = acc[v];
}

// ---------------- main GEMM: m97 structure (128x128, BK=32, global_load_lds) ----------------
__global__ __launch_bounds__(256) void gemm_bf16_kernel(
        const ushort_t* __restrict__ xb, const ushort_t* __restrict__ wb,
        const float* __restrict__ bias, const float* __restrict__ lora_B,
        const float* __restrict__ T, float* __restrict__ out) {

    __shared__ __align__(16) ushort_t As[128][32];
    __shared__ __align__(16) ushort_t Bs[128][32];

    const int t    = threadIdx.x;
    const int lane = t & 63, wv = t >> 6;
    const int wr = wv >> 1, wc = wv & 1;
    const int l15 = lane & 15, lk = lane >> 4;
    const int brow = blockIdx.y * 128;
    const int bcol = blockIdx.x * 128;

    // staging: wave wv owns rows [wv*32, wv*32+32) of As and Bs, as 2 chunks of 16 rows.
    // within a chunk: lane l -> row chunkbase + l/4, elem col (l&3)*8  (linear 1024B)
    const int srow = wv * 32 + (lane >> 2);
    const int scol = (lane & 3) * 8;
    const ushort_t* ga = xb + (size_t)(brow + srow) * IN_F + scol;
    const ushort_t* gb = wb + (size_t)(bcol + srow) * IN_F + scol;
    ushort_t* lA0 = &As[wv * 32][0];
    ushort_t* lA1 = &As[wv * 32 + 16][0];
    ushort_t* lB0 = &Bs[wv * 32][0];
    ushort_t* lB1 = &Bs[wv * 32 + 16][0];

    f32x4 acc[4][4];
#pragma unroll
    for (int m = 0; m < 4; m++)
#pragma unroll
        for (int n = 0; n < 4; n++)
            acc[m][n] = (f32x4){0.f, 0.f, 0.f, 0.f};

    for (int k0 = 0; k0 < IN_F; k0 += 32) {
        gload16(ga + k0,                lA0);
        gload16(ga + k0 + 16 * IN_F,    lA1);
        gload16(gb + k0,                lB0);
        gload16(gb + k0 + 16 * IN_F,    lB1);
        __syncthreads();   // drains vmcnt -> staged data visible

        bf16x8 af[4], bf[4];
#pragma unroll
        for (int m = 0; m < 4; m++) af[m] = *(bf16x8*)&As[wr * 64 + m * 16 + l15][lk * 8];
#pragma unroll
        for (int n = 0; n < 4; n++) bf[n] = *(bf16x8*)&Bs[wc * 64 + n * 16 + l15][lk * 8];

#pragma unroll
        for (int m = 0; m < 4; m++)
#pragma unroll
            for (int n = 0; n < 4; n++)
                acc[m][n] = __builtin_amdgcn_mfma_f32_16x16x32_bf16(af[m], bf[n], acc[m][n], 0, 0, 0);
        __syncthreads();   // compute done before next stage overwrites
    }

    // ---- LoRA rank-update as one extra MFMA K-step (reg-staged, tiny) ----
    const int srow2  = t >> 1;
    const int shalf2 = (t & 1) << 4;
    if (shalf2 == 0) {
        const float* tp = T + (size_t)(brow + srow2) * RANK;
        *(bf16x8*)&As[srow2][0] = pack8(s4(ld4(tp), SCALING), s4(ld4(tp + 4), SCALING));
        *(bf16x8*)&As[srow2][8] = pack8(s4(ld4(tp + 8), SCALING), s4(ld4(tp + 12), SCALING));
        const float* bp = lora_B + (size_t)(bcol + srow2) * RANK;
        *(bf16x8*)&Bs[srow2][0] = pack8(ld4(bp), ld4(bp + 4));
        *(bf16x8*)&Bs[srow2][8] = pack8(ld4(bp + 8), ld4(bp + 12));
    } else {
        bf16x8 z;
#pragma unroll
        for (int i = 0; i < 8; i++) z[i] = 0;
        *(bf16x8*)&As[srow2][16] = z; *(bf16x8*)&As[srow2][24] = z;
        *(bf16x8*)&Bs[srow2][16] = z; *(bf16x8*)&Bs[srow2][24] = z;
    }
    __syncthreads();
    {
        bf16x8 af[4], bf[4];
#pragma unroll
        for (int m = 0; m < 4; m++) af[m] = *(bf16x8*)&As[wr * 64 + m * 16 + l15][lk * 8];
#pragma unroll
        for (int n = 0; n < 4; n++) bf[n] = *(bf16x8*)&Bs[wc * 64 + n * 16 + l15][lk * 8];
#pragma unroll
        for (int m = 0; m < 4; m++)
#pragma unroll
            for (int n = 0; n < 4; n++)
                acc[m][n] = __builtin_amdgcn_mfma_f32_16x16x32_bf16(af[m], bf[n], acc[m][n], 0, 0, 0);
    }

    // ---- epilogue: + bias, write C ----
    const int ocol0 = bcol + wc * 64 + l15;
#pragma unroll
    for (int n = 0; n < 4; n++) {
        const int col = ocol0 + n * 16;
        const float bv = bias[col];
#pragma unroll
        for (int m = 0; m < 4; m++) {
            const int row0 = brow + wr * 64 + m * 16 + lk * 4;
#pragma unroll
            for (int v = 0; v < 4; v++) {
                out[(size_t)(row0 + v) * OUT_F + col] = acc[m][n][v] + bv;
            }
        }
    }
}

// ================= fallback path (round-1, reg-staged fp32) =================
__global__ __launch_bounds__(256) void lora_t_kernel(const float* __restrict__ x,
                                                     const float* __restrict__ lora_A,
                                                     float* __restrict__ T) {
    const int t   = threadIdx.x;
    const int row = blockIdx.x * 16 + (t >> 4);
    const int rr  = t & 15;
    const float* xr = x + (size_t)row * IN_F;
    const float* ar = lora_A + (size_t)rr * IN_F;
    float acc = 0.f;
#pragma unroll 8
    for (int k = 0; k < IN_F; k += 4) {
        float4 xv = ld4(xr + k);
        float4 av = ld4(ar + k);
        acc += xv.x * av.x + xv.y * av.y + xv.z * av.z + xv.w * av.w;
    }
    T[row * RANK + rr] = acc;
}

__global__ __launch_bounds__(256) void lora_gemm_kernel(
        const float* __restrict__ x, const float* __restrict__ w,
        const float* __restrict__ bias, const float* __restrict__ lora_B,
        const float* __restrict__ T, float* __restrict__ out) {

    __shared__ __align__(16) short As[128][32];
    __shared__ __align__(16) short Bs[128][32];

    const int t    = threadIdx.x;
    const int brow = blockIdx.y * 128;
    const int bcol = blockIdx.x * 128;
    const int srow  = t >> 1;
    const int shalf = (t & 1) << 4;
    const float* xa = x + (size_t)(brow + srow) * IN_F + shalf;
    const float* wb = w + (size_t)(bcol + srow) * IN_F + shalf;
    const int lane = t & 63;
    const int wv   = t >> 6;
    const int wr   = wv >> 1, wc = wv & 1;
    const int l15  = lane & 15, lk = lane >> 4;

    f32x4 acc[4][4];
#pragma unroll
    for (int m = 0; m < 4; m++)
#pragma unroll
        for (int n = 0; n < 4; n++)
            acc[m][n] = (f32x4){0.f, 0.f, 0.f, 0.f};

    for (int k0 = 0; k0 < IN_F; k0 += 32) {
        float4 a0 = ld4(xa + k0);      float4 a1 = ld4(xa + k0 + 4);
        float4 a2 = ld4(xa + k0 + 8);  float4 a3 = ld4(xa + k0 + 12);
        float4 b0 = ld4(wb + k0);      float4 b1 = ld4(wb + k0 + 4);
        float4 b2 = ld4(wb + k0 + 8);  float4 b3 = ld4(wb + k0 + 12);

        __syncthreads();
        *(bf16x8*)&As[srow][shalf]     = pack8(a0, a1);
        *(bf16x8*)&As[srow][shalf + 8] = pack8(a2, a3);
        *(bf16x8*)&Bs[srow][shalf]     = pack8(b0, b1);
        *(bf16x8*)&Bs[srow][shalf + 8] = pack8(b2, b3);
        __syncthreads();

        bf16x8 af[4], bf[4];
#pragma unroll
        for (int m = 0; m < 4; m++) af[m] = *(bf16x8*)&As[wr * 64 + m * 16 + l15][lk * 8];
#pragma unroll
        for (int n = 0; n < 4; n++) bf[n] = *(bf16x8*)&Bs[wc * 64 + n * 16 + l15][lk * 8];
#pragma unroll
        for (int m = 0; m < 4; m++)
#pragma unroll
            for (int n = 0; n < 4; n++)
                acc[m][n] = __builtin_amdgcn_mfma_f32_16x16x32_bf16(af[m], bf[n], acc[m][n], 0, 0, 0);
    }

    __syncthreads();
    if (shalf == 0) {
        const float* tp = T + (size_t)(brow + srow) * RANK;
        *(bf16x8*)&As[srow][0] = pack8(s4(ld4(tp), SCALING), s4(ld4(tp + 4), SCALING));
        *(bf16x8*)&As[srow][8] = pack8(s4(ld4(tp + 8), SCALING), s4(ld4(tp + 12), SCALING));
        const float* bp = lora_B + (size_t)(bcol + srow) * RANK;
        *(bf16x8*)&Bs[srow][0] = pack8(ld4(bp), ld4(bp + 4));
        *(bf16x8*)&Bs[srow][8] = pack8(ld4(bp + 8), ld4(bp + 12));
    } else {
        bf16x8 z;
#pragma unroll
        for (int i = 0; i < 8; i++) z[i] = 0;
        *(bf16x8*)&As[srow][16] = z; *(bf16x8*)&As[srow][24] = z;
        *(bf16x8*)&Bs[srow][16] = z; *(bf16x8*)&Bs[srow][24] = z;
    }
    __syncthreads();
    {
        bf16x8 af[4], bf[4];
#pragma unroll
        for (int m = 0; m < 4; m++) af[m] = *(bf16x8*)&As[wr * 64 + m * 16 + l15][lk * 8];
#pragma unroll
        for (int n = 0; n < 4; n++) bf[n] = *(bf16x8*)&Bs[wc * 64 + n * 16 + l15][lk * 8];
#pragma unroll
        for (int m = 0; m < 4; m++)
#pragma unroll
            for (int n = 0; n < 4; n++)
                acc[m][n] = __builtin_amdgcn_mfma_f32_16x16x32_bf16(af[m], bf[n], acc[m][n], 0, 0, 0);
    }

    const int ocol0 = bcol + wc * 64 + l15;
#pragma unroll
    for (int n = 0; n < 4; n++) {
        const int col = ocol0 + n * 16;
        const float bv = bias[col];
#pragma unroll
        for (int m = 0; m < 4; m++) {
            const int row0 = brow + wr * 64 + m * 16 + lk * 4;
#pragma unroll
            for (int v = 0; v < 4; v++) {
                out[(size_t)(row0 + v) * OUT_F + col] = acc[m][n][v] + bv;
            }
        }
    }
}

extern "C" void kernel_launch(void* const* d_in, const int* in_sizes, int n_in,
                              void* d_out, int out_size, void* d_ws, size_t ws_size,
                              hipStream_t stream) {
    const float* x      = (const float*)d_in[0];
    const float* w      = (const float*)d_in[1];
    const float* bias   = (const float*)d_in[2];
    const float* lora_A = (const float*)d_in[3];
    const float* lora_B = (const float*)d_in[4];
    float* out = (float*)d_out;

    // ws layout: [T fp32 512K][A_bf16 128K][W_bf16 33.5M][X_bf16 67M]
    const size_t OFF_T = 0;
    const size_t OFF_A = 524288;
    const size_t OFF_W = 655360;
    const size_t OFF_X = 34209792;
    const size_t WS_NEED = 101318656;

    if (ws_size >= WS_NEED) {
        char* ws = (char*)d_ws;
        float*    T  = (float*)(ws + OFF_T);
        ushort_t* ab = (ushort_t*)(ws + OFF_A);
        ushort_t* wb = (ushort_t*)(ws + OFF_W);
        ushort_t* xb = (ushort_t*)(ws + OFF_X);

        cvt_bf16_kernel<<<2048, 256, 0, stream>>>(x, xb, M_ROWS * IN_F / 8);
        cvt_bf16_kernel<<<1024, 256, 0, stream>>>(w, wb, OUT_F * IN_F / 8);
        cvt_bf16_kernel<<<32,   256, 0, stream>>>(lora_A, ab, RANK * IN_F / 8);

        lora_t_mfma<<<M_ROWS / 64, 256, 0, stream>>>(xb, ab, T);

        dim3 grid(OUT_F / 128, M_ROWS / 128);
        gemm_bf16_kernel<<<grid, 256, 0, stream>>>(xb, wb, bias, lora_B, T, out);
    } else {
        float* T = (float*)d_ws;   // 512 KiB scratch
        lora_t_kernel<<<M_ROWS / 16, 256, 0, stream>>>(x, lora_A, T);
        dim3 grid(OUT_F / 128, M_ROWS / 128);
        lora_gemm_kernel<<<grid, 256, 0, stream>>>(x, w, bias, lora_B, T, out);
    }
}

// Round 3
// 357.642 us; speedup vs baseline: 2.3490x; 1.3144x over previous
//
#include <hip/hip_runtime.h>
#include <hip/hip_bf16.h>

#define IN_F   4096
#define OUT_F  4096
#define M_ROWS 8192
#define RANK   16
#define SCALING 2.0f

#define BM 256
#define BN 256
#define BK 64
#define NT (IN_F / BK)   // 64 K-tiles

typedef __attribute__((ext_vector_type(8))) short bf16x8;
typedef __attribute__((ext_vector_type(4))) float f32x4;
typedef unsigned short ushort_t;

__device__ __forceinline__ short f2b(float f) {
    union { float f; unsigned u; } c; c.f = f;
    unsigned r = (c.u + 0x7FFFu + ((c.u >> 16) & 1u)) >> 16;
    return (short)r;
}

__device__ __forceinline__ float4 ld4(const float* p) { return *(const float4*)p; }

__device__ __forceinline__ float4 s4(float4 v, float s) {
    v.x *= s; v.y *= s; v.z *= s; v.w *= s; return v;
}

__device__ __forceinline__ bf16x8 pack8(float4 a, float4 b) {
    bf16x8 r;
    r[0] = f2b(a.x); r[1] = f2b(a.y); r[2] = f2b(a.z); r[3] = f2b(a.w);
    r[4] = f2b(b.x); r[5] = f2b(b.y); r[6] = f2b(b.z); r[7] = f2b(b.w);
    return r;
}

__device__ __forceinline__ void gload16(const void* g, void* l) {
    __builtin_amdgcn_global_load_lds(
        (const __attribute__((address_space(1))) unsigned int*)g,
        (__attribute__((address_space(3))) unsigned int*)l, 16, 0, 0);
}

// ---------------- fp32 -> bf16 convert ----------------
__global__ __launch_bounds__(256) void cvt_bf16_kernel(const float* __restrict__ in,
                                                       ushort_t* __restrict__ out, int n8) {
    int i = blockIdx.x * blockDim.x + threadIdx.x;
    const int stride = gridDim.x * blockDim.x;
    for (; i < n8; i += stride) {
        const float* p = in + (size_t)i * 8;
        *(bf16x8*)(out + (size_t)i * 8) = pack8(ld4(p), ld4(p + 4));
    }
}

// ---------------- T = x @ lora_A^T via MFMA ----------------
__global__ __launch_bounds__(256) void lora_t_mfma(const ushort_t* __restrict__ xb,
                                                   const ushort_t* __restrict__ ab,
                                                   float* __restrict__ T) {
    const int t = threadIdx.x, lane = t & 63, wv = t >> 6;
    const int r0 = blockIdx.x * 64 + wv * 16;
    const int l15 = lane & 15, lk = lane >> 4;
    const ushort_t* xr = xb + (size_t)(r0 + l15) * IN_F + lk * 8;
    const ushort_t* ar = ab + (size_t)l15 * IN_F + lk * 8;
    f32x4 acc = (f32x4){0.f, 0.f, 0.f, 0.f};
    for (int k0 = 0; k0 < IN_F; k0 += 32) {
        bf16x8 af = *(const bf16x8*)(xr + k0);
        bf16x8 bf = *(const bf16x8*)(ar + k0);
        acc = __builtin_amdgcn_mfma_f32_16x16x32_bf16(af, bf, acc, 0, 0, 0);
    }
#pragma unroll
    for (int v = 0; v < 4; v++)
        T[(size_t)(r0 + lk * 4 + v) * RANK + l15] = acc[v];
}

// ============ main GEMM: 256x256 tile, BK=64, 8-wave, 8-phase counted-vmcnt ============
__global__ __launch_bounds__(512, 1) void gemm8p(
        const ushort_t* __restrict__ xb, const ushort_t* __restrict__ wb,
        const float* __restrict__ bias, const float* __restrict__ lora_B,
        const float* __restrict__ T, float* __restrict__ out) {

    __shared__ __align__(16) ushort_t As[2][BM * BK];   // 64 KiB
    __shared__ __align__(16) ushort_t Bs[2][BN * BK];   // 64 KiB

    const int tid  = threadIdx.x;
    const int lane = tid & 63, wv = tid >> 6;
    const int wm = wv >> 2, wn = wv & 3;          // 2 x 4 wave grid; wave tile 128x64
    const int l15 = lane & 15, lk = lane >> 4;

    // XCD-aware block swizzle (512 wgs, divisible by 8)
    const int bid = blockIdx.x;
    const int swz = (bid & 7) * 64 + (bid >> 3);
    const int by = swz >> 4, bx = swz & 15;       // 32 x 16 tile grid
    const int brow = by * BM, bcol = bx * BN;

    // ---- staging coords (per-thread, constant over tiles) ----
    // half-tile = 128 rows x 64 cols = 16KB; thread covers 2 linear 16B chunks
    const int off0 = wv * 2048 + lane * 16;
    const int off1 = off0 + 1024;
    const int row0 = off0 >> 7, row1 = off1 >> 7;
    const int sc0 = ((off0 & 127) ^ ((row0 & 7) << 4)) >> 1;  // pre-swizzled src elem col
    const int sc1 = ((off1 & 127) ^ ((row1 & 7) << 4)) >> 1;
    const int ldst = wv * 1024;                   // elems within half-region

    // STAGE one half-tile: mat row base rb, half h (0/1), k-tile kt, LDS buffer bf
#define STAGE_A(h, kt, bf) do { \
    gload16(xb + (size_t)(brow + (h)*128 + row0) * IN_F + (kt)*64 + sc0, &As[bf][(h)*8192 + ldst]); \
    gload16(xb + (size_t)(brow + (h)*128 + row1) * IN_F + (kt)*64 + sc1, &As[bf][(h)*8192 + ldst + 512]); \
  } while (0)
#define STAGE_B(h, kt, bf) do { \
    gload16(wb + (size_t)(bcol + (h)*128 + row0) * IN_F + (kt)*64 + sc0, &Bs[bf][(h)*8192 + ldst]); \
    gload16(wb + (size_t)(bcol + (h)*128 + row1) * IN_F + (kt)*64 + sc1, &Bs[bf][(h)*8192 + ldst + 512]); \
  } while (0)

    // swizzled ds_read col offsets (bytes) for ksub 0/1
    const int cb0 = (lk * 16) ^ ((l15 & 7) << 4);
    const int cb1 = (64 + lk * 16) ^ ((l15 & 7) << 4);

#define AFR(bf, r, cb) (*(const bf16x8*)((const char*)&As[bf][0] + (r) * 128 + (cb)))
#define BFR(bf, c, cb) (*(const bf16x8*)((const char*)&Bs[bf][0] + (c) * 128 + (cb)))

    f32x4 acc[8][4];
#pragma unroll
    for (int m = 0; m < 8; m++)
#pragma unroll
        for (int n = 0; n < 4; n++) acc[m][n] = (f32x4){0.f, 0.f, 0.f, 0.f};

    bf16x8 af[8], bf0[4], bf1[4];

    // ---- prologue: tile0 (8 loads) + B0/A0 of tile1 (4 loads) ----
    STAGE_A(0, 0, 0); STAGE_A(1, 0, 0);
    STAGE_B(0, 0, 0); STAGE_B(1, 0, 0);
    STAGE_B(0, 1, 1); STAGE_A(0, 1, 1);
    asm volatile("s_waitcnt vmcnt(4)" ::: "memory");
    __builtin_amdgcn_s_barrier();

    for (int t = 0; t < NT; ++t) {
        const int cur = t & 1, nxt = cur ^ 1;
        const int kt1 = (t + 1 < NT) ? t + 1 : NT - 1;
        const int kt2 = (t + 2 < NT) ? t + 2 : NT - 1;
        const int am = wm * 128, bn = wn * 64;

        // ---------- phase 1: quad(mh0, nh0) ----------
#pragma unroll
        for (int mi = 0; mi < 4; mi++) {
            af[mi * 2]     = AFR(cur, am + mi * 16 + l15, cb0);
            af[mi * 2 + 1] = AFR(cur, am + mi * 16 + l15, cb1);
        }
#pragma unroll
        for (int ni = 0; ni < 2; ni++) {
            bf0[ni * 2]     = BFR(cur, bn + ni * 16 + l15, cb0);
            bf0[ni * 2 + 1] = BFR(cur, bn + ni * 16 + l15, cb1);
        }
        STAGE_B(1, kt1, nxt);
        asm volatile("" ::: "memory");
        __builtin_amdgcn_s_barrier();
        __builtin_amdgcn_sched_barrier(0);
        __builtin_amdgcn_s_setprio(1);
#pragma unroll
        for (int mi = 0; mi < 4; mi++)
#pragma unroll
            for (int ni = 0; ni < 2; ni++)
#pragma unroll
                for (int ks = 0; ks < 2; ks++)
                    acc[mi][ni] = __builtin_amdgcn_mfma_f32_16x16x32_bf16(
                        af[mi * 2 + ks], bf0[ni * 2 + ks], acc[mi][ni], 0, 0, 0);
        __builtin_amdgcn_s_setprio(0);
        asm volatile("" ::: "memory");
        __builtin_amdgcn_s_barrier();

        // ---------- phase 2: quad(mh0, nh1) ----------
#pragma unroll
        for (int ni = 0; ni < 2; ni++) {
            bf1[ni * 2]     = BFR(cur, bn + 32 + ni * 16 + l15, cb0);
            bf1[ni * 2 + 1] = BFR(cur, bn + 32 + ni * 16 + l15, cb1);
        }
        STAGE_A(1, kt1, nxt);
        asm volatile("" ::: "memory");
        __builtin_amdgcn_s_barrier();
        __builtin_amdgcn_sched_barrier(0);
        __builtin_amdgcn_s_setprio(1);
#pragma unroll
        for (int mi = 0; mi < 4; mi++)
#pragma unroll
            for (int ni = 0; ni < 2; ni++)
#pragma unroll
                for (int ks = 0; ks < 2; ks++)
                    acc[mi][2 + ni] = __builtin_amdgcn_mfma_f32_16x16x32_bf16(
                        af[mi * 2 + ks], bf1[ni * 2 + ks], acc[mi][2 + ni], 0, 0, 0);
        __builtin_amdgcn_s_setprio(0);
        asm volatile("" ::: "memory");
        __builtin_amdgcn_s_barrier();

        // ---------- phase 3: quad(mh1, nh1) ----------
#pragma unroll
        for (int mi = 0; mi < 4; mi++) {
            af[mi * 2]     = AFR(cur, am + 64 + mi * 16 + l15, cb0);
            af[mi * 2 + 1] = AFR(cur, am + 64 + mi * 16 + l15, cb1);
        }
        STAGE_B(0, kt2, cur);
        asm volatile("" ::: "memory");
        __builtin_amdgcn_s_barrier();
        __builtin_amdgcn_sched_barrier(0);
        __builtin_amdgcn_s_setprio(1);
#pragma unroll
        for (int mi = 0; mi < 4; mi++)
#pragma unroll
            for (int ni = 0; ni < 2; ni++)
#pragma unroll
                for (int ks = 0; ks < 2; ks++)
                    acc[4 + mi][2 + ni] = __builtin_amdgcn_mfma_f32_16x16x32_bf16(
                        af[mi * 2 + ks], bf1[ni * 2 + ks], acc[4 + mi][2 + ni], 0, 0, 0);
        __builtin_amdgcn_s_setprio(0);
        asm volatile("" ::: "memory");
        __builtin_amdgcn_s_barrier();

        // ---------- phase 4: quad(mh1, nh0) ----------
        STAGE_A(0, kt2, cur);
        asm volatile("" ::: "memory");
        __builtin_amdgcn_s_barrier();
        __builtin_amdgcn_sched_barrier(0);
        __builtin_amdgcn_s_setprio(1);
#pragma unroll
        for (int mi = 0; mi < 4; mi++)
#pragma unroll
            for (int ni = 0; ni < 2; ni++)
#pragma unroll
                for (int ks = 0; ks < 2; ks++)
                    acc[4 + mi][ni] = __builtin_amdgcn_mfma_f32_16x16x32_bf16(
                        af[mi * 2 + ks], bf0[ni * 2 + ks], acc[4 + mi][ni], 0, 0, 0);
        __builtin_amdgcn_s_setprio(0);
        asm volatile("s_waitcnt vmcnt(4)" ::: "memory");
        __builtin_amdgcn_s_barrier();
    }

    // ---- LoRA rank-update: one K=32 MFMA step (linear LDS, reg-staged) ----
    asm volatile("s_waitcnt vmcnt(0)" ::: "memory");
    __builtin_amdgcn_s_barrier();
    {
        const int r = tid >> 1, hh = tid & 1;
        ushort_t* LA = &As[0][0];
        ushort_t* LB = &Bs[0][0];
        if (hh == 0) {
            const float* tp = T + (size_t)(brow + r) * RANK;
            *(bf16x8*)&LA[r * 32]     = pack8(s4(ld4(tp), SCALING), s4(ld4(tp + 4), SCALING));
            *(bf16x8*)&LA[r * 32 + 8] = pack8(s4(ld4(tp + 8), SCALING), s4(ld4(tp + 12), SCALING));
            const float* bp = lora_B + (size_t)(bcol + r) * RANK;
            *(bf16x8*)&LB[r * 32]     = pack8(ld4(bp), ld4(bp + 4));
            *(bf16x8*)&LB[r * 32 + 8] = pack8(ld4(bp + 8), ld4(bp + 12));
        } else {
            bf16x8 z;
#pragma unroll
            for (int i = 0; i < 8; i++) z[i] = 0;
            *(bf16x8*)&LA[r * 32 + 16] = z; *(bf16x8*)&LA[r * 32 + 24] = z;
            *(bf16x8*)&LB[r * 32 + 16] = z; *(bf16x8*)&LB[r * 32 + 24] = z;
        }
    }
    __syncthreads();
    {
        const ushort_t* LA = &As[0][0];
        const ushort_t* LB = &Bs[0][0];
        bf16x8 bfL[4];
#pragma unroll
        for (int n = 0; n < 4; n++)
            bfL[n] = *(const bf16x8*)&LB[(wn * 64 + n * 16 + l15) * 32 + lk * 8];
#pragma unroll
        for (int m = 0; m < 8; m++) {
            bf16x8 afL = *(const bf16x8*)&LA[(wm * 128 + m * 16 + l15) * 32 + lk * 8];
#pragma unroll
            for (int n = 0; n < 4; n++)
                acc[m][n] = __builtin_amdgcn_mfma_f32_16x16x32_bf16(afL, bfL[n], acc[m][n], 0, 0, 0);
        }
    }

    // ---- epilogue: + bias, store ----
#pragma unroll
    for (int n = 0; n < 4; n++) {
        const int col = bcol + wn * 64 + n * 16 + l15;
        const float bv = bias[col];
#pragma unroll
        for (int m = 0; m < 8; m++) {
            const int row0_ = brow + wm * 128 + m * 16 + lk * 4;
#pragma unroll
            for (int v = 0; v < 4; v++)
                out[(size_t)(row0_ + v) * OUT_F + col] = acc[m][n][v] + bv;
        }
    }
#undef STAGE_A
#undef STAGE_B
#undef AFR
#undef BFR
}

// ================= fallback path (round-1, reg-staged fp32) =================
__global__ __launch_bounds__(256) void lora_t_kernel(const float* __restrict__ x,
                                                     const float* __restrict__ lora_A,
                                                     float* __restrict__ T) {
    const int t   = threadIdx.x;
    const int row = blockIdx.x * 16 + (t >> 4);
    const int rr  = t & 15;
    const float* xr = x + (size_t)row * IN_F;
    const float* ar = lora_A + (size_t)rr * IN_F;
    float acc = 0.f;
#pragma unroll 8
    for (int k = 0; k < IN_F; k += 4) {
        float4 xv = ld4(xr + k);
        float4 av = ld4(ar + k);
        acc += xv.x * av.x + xv.y * av.y + xv.z * av.z + xv.w * av.w;
    }
    T[row * RANK + rr] = acc;
}

__global__ __launch_bounds__(256) void lora_gemm_kernel(
        const float* __restrict__ x, const float* __restrict__ w,
        const float* __restrict__ bias, const float* __restrict__ lora_B,
        const float* __restrict__ T, float* __restrict__ out) {

    __shared__ __align__(16) short As[128][32];
    __shared__ __align__(16) short Bs[128][32];

    const int t    = threadIdx.x;
    const int brow = blockIdx.y * 128;
    const int bcol = blockIdx.x * 128;
    const int srow  = t >> 1;
    const int shalf = (t & 1) << 4;
    const float* xa = x + (size_t)(brow + srow) * IN_F + shalf;
    const float* wb = w + (size_t)(bcol + srow) * IN_F + shalf;
    const int lane = t & 63;
    const int wv   = t >> 6;
    const int wr   = wv >> 1, wc = wv & 1;
    const int l15  = lane & 15, lk = lane >> 4;

    f32x4 acc[4][4];
#pragma unroll
    for (int m = 0; m < 4; m++)
#pragma unroll
        for (int n = 0; n < 4; n++)
            acc[m][n] = (f32x4){0.f, 0.f, 0.f, 0.f};

    for (int k0 = 0; k0 < IN_F; k0 += 32) {
        float4 a0 = ld4(xa + k0);      float4 a1 = ld4(xa + k0 + 4);
        float4 a2 = ld4(xa + k0 + 8);  float4 a3 = ld4(xa + k0 + 12);
        float4 b0 = ld4(wb + k0);      float4 b1 = ld4(wb + k0 + 4);
        float4 b2 = ld4(wb + k0 + 8);  float4 b3 = ld4(wb + k0 + 12);

        __syncthreads();
        *(bf16x8*)&As[srow][shalf]     = pack8(a0, a1);
        *(bf16x8*)&As[srow][shalf + 8] = pack8(a2, a3);
        *(bf16x8*)&Bs[srow][shalf]     = pack8(b0, b1);
        *(bf16x8*)&Bs[srow][shalf + 8] = pack8(b2, b3);
        __syncthreads();

        bf16x8 af[4], bf[4];
#pragma unroll
        for (int m = 0; m < 4; m++) af[m] = *(bf16x8*)&As[wr * 64 + m * 16 + l15][lk * 8];
#pragma unroll
        for (int n = 0; n < 4; n++) bf[n] = *(bf16x8*)&Bs[wc * 64 + n * 16 + l15][lk * 8];
#pragma unroll
        for (int m = 0; m < 4; m++)
#pragma unroll
            for (int n = 0; n < 4; n++)
                acc[m][n] = __builtin_amdgcn_mfma_f32_16x16x32_bf16(af[m], bf[n], acc[m][n], 0, 0, 0);
    }

    __syncthreads();
    if (shalf == 0) {
        const float* tp = T + (size_t)(brow + srow) * RANK;
        *(bf16x8*)&As[srow][0] = pack8(s4(ld4(tp), SCALING), s4(ld4(tp + 4), SCALING));
        *(bf16x8*)&As[srow][8] = pack8(s4(ld4(tp + 8), SCALING), s4(ld4(tp + 12), SCALING));
        const float* bp = lora_B + (size_t)(bcol + srow) * RANK;
        *(bf16x8*)&Bs[srow][0] = pack8(ld4(bp), ld4(bp + 4));
        *(bf16x8*)&Bs[srow][8] = pack8(ld4(bp + 8), ld4(bp + 12));
    } else {
        bf16x8 z;
#pragma unroll
        for (int i = 0; i < 8; i++) z[i] = 0;
        *(bf16x8*)&As[srow][16] = z; *(bf16x8*)&As[srow][24] = z;
        *(bf16x8*)&Bs[srow][16] = z; *(bf16x8*)&Bs[srow][24] = z;
    }
    __syncthreads();
    {
        bf16x8 af[4], bf[4];
#pragma unroll
        for (int m = 0; m < 4; m++) af[m] = *(bf16x8*)&As[wr * 64 + m * 16 + l15][lk * 8];
#pragma unroll
        for (int n = 0; n < 4; n++) bf[n] = *(bf16x8*)&Bs[wc * 64 + n * 16 + l15][lk * 8];
#pragma unroll
        for (int m = 0; m < 4; m++)
#pragma unroll
            for (int n = 0; n < 4; n++)
                acc[m][n] = __builtin_amdgcn_mfma_f32_16x16x32_bf16(af[m], bf[n], acc[m][n], 0, 0, 0);
    }

    const int ocol0 = bcol + wc * 64 + l15;
#pragma unroll
    for (int n = 0; n < 4; n++) {
        const int col = ocol0 + n * 16;
        const float bv = bias[col];
#pragma unroll
        for (int m = 0; m < 4; m++) {
            const int row0 = brow + wr * 64 + m * 16 + lk * 4;
#pragma unroll
            for (int v = 0; v < 4; v++) {
                out[(size_t)(row0 + v) * OUT_F + col] = acc[m][n][v] + bv;
            }
        }
    }
}

extern "C" void kernel_launch(void* const* d_in, const int* in_sizes, int n_in,
                              void* d_out, int out_size, void* d_ws, size_t ws_size,
                              hipStream_t stream) {
    const float* x      = (const float*)d_in[0];
    const float* w      = (const float*)d_in[1];
    const float* bias   = (const float*)d_in[2];
    const float* lora_A = (const float*)d_in[3];
    const float* lora_B = (const float*)d_in[4];
    float* out = (float*)d_out;

    const size_t OFF_T = 0;
    const size_t OFF_A = 524288;
    const size_t OFF_W = 655360;
    const size_t OFF_X = 34209792;
    const size_t WS_NEED = 101318656;

    if (ws_size >= WS_NEED) {
        char* ws = (char*)d_ws;
        float*    T  = (float*)(ws + OFF_T);
        ushort_t* ab = (ushort_t*)(ws + OFF_A);
        ushort_t* wbp = (ushort_t*)(ws + OFF_W);
        ushort_t* xbp = (ushort_t*)(ws + OFF_X);

        cvt_bf16_kernel<<<2048, 256, 0, stream>>>(x, xbp, M_ROWS * IN_F / 8);
        cvt_bf16_kernel<<<1024, 256, 0, stream>>>(w, wbp, OUT_F * IN_F / 8);
        cvt_bf16_kernel<<<32,   256, 0, stream>>>(lora_A, ab, RANK * IN_F / 8);

        lora_t_mfma<<<M_ROWS / 64, 256, 0, stream>>>(xbp, ab, T);

        gemm8p<<<(M_ROWS / BM) * (OUT_F / BN), 512, 0, stream>>>(xbp, wbp, bias, lora_B, T, out);
    } else {
        float* T = (float*)d_ws;
        lora_t_kernel<<<M_ROWS / 16, 256, 0, stream>>>(x, lora_A, T);
        dim3 grid(OUT_F / 128, M_ROWS / 128);
        lora_gemm_kernel<<<grid, 128 * 2, 0, stream>>>(x, w, bias, lora_B, T, out);
    }
}